// Round 6
// baseline (258.281 us; speedup 1.0000x reference)
//
#include <hip/hip_runtime.h>
#include <hip/hip_cooperative_groups.h>

namespace cg = cooperative_groups;

namespace {
constexpr int kB = 64, kH = 512, kW = 512;
constexpr float kEps = 1e-6f;
constexpr int kMaxIt = 1000;
constexpr int kBlk = 256;   // 4 blocks per batch; block owns 128 rows
constexpr int kThr = 1024;  // 16 waves; 8 rows per wave; 8x8 K elems per thread
constexpr int kWaves = 16;
}

// ---- cross-block state (agent-scope atomic access only; tag-guarded rings) ----
__device__ float    g_KTp[2][kB][4][kW];  // ring-2 per-(batch,quarter) col partials
__device__ float    g_err[8][kB];         // ring-8 per-batch max|beta-c|
__device__ unsigned g_etag[kB];           // last iteration whose err is published
__device__ unsigned g_ptag[kB][16];       // [b][q] partial tags, 64B per batch

__device__ __forceinline__ float waveRedSum(float v) {
  #pragma unroll
  for (int o = 32; o; o >>= 1) v += __shfl_xor(v, o);
  return v;
}
__device__ __forceinline__ float waveRedMax(float v) {
  #pragma unroll
  for (int o = 32; o; o >>= 1) v = fmaxf(v, __shfl_xor(v, o));
  return v;
}
__device__ __forceinline__ float waveRedMin(float v) {
  #pragma unroll
  for (int o = 32; o; o >>= 1) v = fminf(v, __shfl_xor(v, o));
  return v;
}

__global__ __launch_bounds__(kThr, 4)
void sinkhorn_kernel(const float* __restrict__ M, const float* __restrict__ r,
                     const float* __restrict__ c, float* __restrict__ P) {
  __shared__ float s_part[kWaves][kW];  // 32 KB column partials
  __shared__ float s_v[4][kW];          // v ring: v_t at slot t&3
  __shared__ float s_u[4][128];         // u ring: u_t at slot t&3 (block's 128 rows)
  __shared__ float s_cn[kW];
  __shared__ float s_rn[128];
  __shared__ float s_red[kWaves];
  __shared__ float s_bc[2];

  const int tid = threadIdx.x, bid = blockIdx.x;
  const int b = bid >> 2;      // batch
  const int q = bid & 3;       // row-quarter
  const int w = tid >> 6, lane = tid & 63;
  const int row0 = q * 128 + w * 8;

  // ---- zero tags; publish with the ONLY fenced sync ----
  if (tid == 0) {
    __hip_atomic_store(&g_ptag[b][q], 0u, __ATOMIC_RELAXED, __HIP_MEMORY_SCOPE_AGENT);
    if (q == 0)
      __hip_atomic_store(&g_etag[b], 0u, __ATOMIC_RELAXED, __HIP_MEMORY_SCOPE_AGENT);
  }
  cg::this_grid().sync();

  // ---- setup: r_n, c_n, v_1 = u_0 = 1; K = exp(rowmin - M) into registers ----
  {
    float rv = (tid < kH) ? r[(size_t)b * kH + tid] : 0.f;
    float ws = waveRedSum(rv);
    if (lane == 0) s_red[w] = ws;
    __syncthreads();
    if (tid == 0) {
      float s = s_red[0];
      #pragma unroll
      for (int i = 1; i < kWaves; ++i) s += s_red[i];
      s_bc[0] = s;
    }
    __syncthreads();
    float rsum = s_bc[0];
    if (tid < 128) s_rn[tid] = r[(size_t)b * kH + q * 128 + tid] / rsum;
    __syncthreads();

    float cv = (tid < kW) ? c[(size_t)b * kW + tid] : 0.f;
    ws = waveRedSum(cv);
    if (lane == 0) s_red[w] = ws;
    __syncthreads();
    if (tid == 0) {
      float s = s_red[0];
      #pragma unroll
      for (int i = 1; i < kWaves; ++i) s += s_red[i];
      s_bc[0] = s;
    }
    __syncthreads();
    float csum = s_bc[0];
    if (tid < kW) {
      s_cn[tid] = c[(size_t)b * kW + tid] / csum;
      s_v[1][tid] = 1.0f;            // v_1
    }
    if (tid < 128) s_u[0][tid] = 1.0f;  // u_0
  }

  float4 kreg[8][2];   // this thread's 8 rows x 8 cols of K (registers/AGPRs)
  #pragma unroll
  for (int rr = 0; rr < 8; ++rr) {
    const float4* Mr = (const float4*)(M + ((size_t)b * kH + row0 + rr) * kW);
    float4 a = Mr[lane], d = Mr[64 + lane];
    float mn = fminf(fminf(fminf(a.x, a.y), fminf(a.z, a.w)),
                     fminf(fminf(d.x, d.y), fminf(d.z, d.w)));
    mn = waveRedMin(mn);
    float4 ka, kb;
    ka.x = expf(mn - a.x); ka.y = expf(mn - a.y);
    ka.z = expf(mn - a.z); ka.w = expf(mn - a.w);
    kb.x = expf(mn - d.x); kb.y = expf(mn - d.y);
    kb.z = expf(mn - d.z); kb.w = expf(mn - d.w);
    kreg[rr][0] = ka; kreg[rr][1] = kb;
  }
  __syncthreads();

  // ---- iteration loop: per-batch tag sync; lag-2 global verdict off-path ----
  int fin_u_slot = 0, fin_v_slot = 0;
  for (int t = 1;; ++t) {
    const int p = t & 3;   // v_t / u_t slot
    const int h = t & 1;   // KTp slot
    // row pass: u_t from u_{t-1} (LDS ring), column partials
    const float4* v4 = (const float4*)s_v[p];
    float4 va = v4[lane], vb = v4[64 + lane];
    float4 cp0 = make_float4(0.f, 0.f, 0.f, 0.f);
    float4 cp1 = make_float4(0.f, 0.f, 0.f, 0.f);
    float u_cur[8];
    #pragma unroll
    for (int rr = 0; rr < 8; ++rr) {
      float4 k0 = kreg[rr][0], k1 = kreg[rr][1];
      float s = k0.x * va.x + k0.y * va.y + k0.z * va.z + k0.w * va.w +
                k1.x * vb.x + k1.y * vb.y + k1.z * vb.z + k1.w * vb.w;
      s = waveRedSum(s);
      float up = s_u[(t - 1) & 3][w * 8 + rr];
      float al = up * s;
      al = (al == 0.f) ? kEps : al;
      float un = up / al * s_rn[w * 8 + rr];
      u_cur[rr] = un;
      cp0.x = fmaf(un, k0.x, cp0.x); cp0.y = fmaf(un, k0.y, cp0.y);
      cp0.z = fmaf(un, k0.z, cp0.z); cp0.w = fmaf(un, k0.w, cp0.w);
      cp1.x = fmaf(un, k1.x, cp1.x); cp1.y = fmaf(un, k1.y, cp1.y);
      cp1.z = fmaf(un, k1.z, cp1.z); cp1.w = fmaf(un, k1.w, cp1.w);
    }
    if (lane == 0) {
      #pragma unroll
      for (int rr = 0; rr < 8; ++rr) s_u[p][w * 8 + rr] = u_cur[rr];
    }
    float4* pp = (float4*)&s_part[w][0];
    pp[lane] = cp0; pp[64 + lane] = cp1;
    __syncthreads();                       // A0: s_part complete
    if (tid < kW) {
      float s = 0.f;
      #pragma unroll
      for (int ww = 0; ww < kWaves; ++ww) s += s_part[ww][tid];
      __hip_atomic_store(&g_KTp[h][b][q][tid], s,
                         __ATOMIC_RELAXED, __HIP_MEMORY_SCOPE_AGENT);
    }
    __syncthreads();                       // A: all KTp stores drained (vmcnt)
    if (tid == 0)
      __hip_atomic_store(&g_ptag[b][q], (unsigned)t,
                         __ATOMIC_RELAXED, __HIP_MEMORY_SCOPE_AGENT);
    if (w == 0) {
      // peer wait: the batch's 4 partial tags reach t
      for (;;) {
        unsigned tg = (unsigned)t;
        if (lane < 4)
          tg = __hip_atomic_load(&g_ptag[b][lane],
                                 __ATOMIC_RELAXED, __HIP_MEMORY_SCOPE_AGENT);
        if (__all(tg >= (unsigned)t)) break;
        __builtin_amdgcn_s_sleep(1);
      }
    } else if (w == 15 && t >= 3) {
      // lag-2 global verdict, overlapped: max over batches of err(t-2)
      unsigned need = (unsigned)(t - 2);
      for (;;) {
        unsigned tg = __hip_atomic_load(&g_etag[lane],
                                        __ATOMIC_RELAXED, __HIP_MEMORY_SCOPE_AGENT);
        if (__all(tg >= need)) break;
        __builtin_amdgcn_s_sleep(1);
      }
      float e = __hip_atomic_load(&g_err[(t - 2) & 7][lane],
                                  __ATOMIC_RELAXED, __HIP_MEMORY_SCOPE_AGENT);
      e = waveRedMax(e);
      if (lane == 0) s_bc[1] = e;
    }
    __syncthreads();                       // B: partials ready + verdict in s_bc[1]
    // column finish: beta_t, v_{t+1}, err_t (fixed-order deterministic sums)
    float err = 0.f;
    if (tid < kW) {
      float kt = 0.f;
      #pragma unroll
      for (int qq = 0; qq < 4; ++qq)
        kt += __hip_atomic_load(&g_KTp[h][b][qq][tid],
                                __ATOMIC_RELAXED, __HIP_MEMORY_SCOPE_AGENT);
      float vt = s_v[p][tid];
      float beta = vt * kt;
      beta = (beta == 0.f) ? kEps : beta;
      float cn = s_cn[tid];
      s_v[(t + 1) & 3][tid] = vt / beta * cn;
      err = fabsf(beta - cn);
    }
    err = waveRedMax(err);
    if (lane == 0) s_red[w] = err;
    __syncthreads();                       // C: s_red + s_v[t+1] complete
    if (tid == 0 && q == 0) {
      float mx = s_red[0];
      #pragma unroll
      for (int i = 1; i < kWaves; ++i) mx = fmaxf(mx, s_red[i]);
      __hip_atomic_store(&g_err[t & 7][b], mx,
                         __ATOMIC_RELAXED, __HIP_MEMORY_SCOPE_AGENT);
      asm volatile("s_waitcnt vmcnt(0)" ::: "memory");   // err before tag
      __hip_atomic_store(&g_etag[b], (unsigned)t,
                         __ATOMIC_RELAXED, __HIP_MEMORY_SCOPE_AGENT);
    }
    if (t >= 3 && s_bc[1] <= kEps) {   // done(t-2): P = u_{t-2} K v_{t-2}
      fin_u_slot = (t - 2) & 3;
      fin_v_slot = (t - 2) & 3;
      break;
    }
    if (t == kMaxIt + 2) {             // never converged: P = u_1000 K v_1001
      fin_u_slot = kMaxIt & 3;
      fin_v_slot = (kMaxIt + 1) & 3;
      break;
    }
  }

  // ---- final: P = diag(u_fin) K diag(v_fin), K straight from registers ----
  float ufin[8];
  #pragma unroll
  for (int rr = 0; rr < 8; ++rr) ufin[rr] = s_u[fin_u_slot][w * 8 + rr];
  const float4* vf4 = (const float4*)s_v[fin_v_slot];
  float4 vfa = vf4[lane], vfb = vf4[64 + lane];
  #pragma unroll
  for (int rr = 0; rr < 8; ++rr) {
    float4 k0 = kreg[rr][0], k1 = kreg[rr][1];
    float un = ufin[rr];
    k0.x = un * k0.x * vfa.x; k0.y = un * k0.y * vfa.y;
    k0.z = un * k0.z * vfa.z; k0.w = un * k0.w * vfa.w;
    k1.x = un * k1.x * vfb.x; k1.y = un * k1.y * vfb.y;
    k1.z = un * k1.z * vfb.z; k1.w = un * k1.w * vfb.w;
    float4* Pr = (float4*)(P + ((size_t)b * kH + row0 + rr) * kW);
    Pr[lane] = k0; Pr[64 + lane] = k1;
  }
}

extern "C" void kernel_launch(void* const* d_in, const int* in_sizes, int n_in,
                              void* d_out, int out_size, void* d_ws, size_t ws_size,
                              hipStream_t stream) {
  (void)in_sizes; (void)n_in; (void)d_ws; (void)ws_size; (void)out_size;
  const float* M = (const float*)d_in[0];
  const float* r = (const float*)d_in[1];
  const float* c = (const float*)d_in[2];
  float* P = (float*)d_out;
  void* args[] = { (void*)&M, (void*)&r, (void*)&c, (void*)&P };
  hipLaunchCooperativeKernel((const void*)sinkhorn_kernel, dim3(kBlk), dim3(kThr),
                             args, 0, stream);
}